// Round 3
// baseline (159.651 us; speedup 1.0000x reference)
//
#include <hip/hip_runtime.h>

// Problem constants: x [8,128,96,96] fp32, W [384,128] fp32, out [8,128,96,96] fp32.
#define NB     8
#define CIN    128
#define HEADS  4
#define DHEAD  32
#define HDIM   96
#define WDIM   96
#define HW     9216

// Fused-kernel tile geometry. One block = one (b, head, 8x16 spatial tile).
#define TH     8                 // interior rows per block
#define TW     16                // interior cols per block
#define HR     (TH + 2)          // halo rows = 10
#define HC     (TW + 2)          // halo cols = 18
#define HP     (HR * HC)         // halo positions = 180
#define NT     12                // position tiles of 16 (192 >= 180, pad OOB)
#define NPOS   (NT * 16)         // 192
#define QP     (TH * TW)         // 128 interior positions

typedef __bf16 bf16x8 __attribute__((ext_vector_type(8)));
typedef float  f32x4  __attribute__((ext_vector_type(4)));

__device__ __forceinline__ unsigned f2bf(float f) {
  unsigned u = __float_as_uint(f);
  return (u + 0x7fffu + ((u >> 16) & 1u)) >> 16;   // RNE
}
__device__ __forceinline__ unsigned pack2(float a, float b) {
  return f2bf(a) | (f2bf(b) << 16);
}
__device__ __forceinline__ float bflo(unsigned u) { return __uint_as_float(u << 16); }
__device__ __forceinline__ float bfhi(unsigned u) { return __uint_as_float(u & 0xffff0000u); }

// ---------------------------------------------------------------------------
// Prep: pack W [384][128] fp32 into A-fragment-ordered bf16 global buffer.
// Frag (ot,kb): lane l holds A[o=ot*16+(l&15)][c=kb*32+(l>>4)*8+j], j=0..7 (16B).
// ---------------------------------------------------------------------------
__global__ __launch_bounds__(256) void wpack_kernel(const float* __restrict__ W,
                                                    uint4* __restrict__ Wf) {
  const int u = blockIdx.x * 256 + threadIdx.x;   // 0..6143 = 24 ot * 4 kb * 64 lanes
  const int lane = u & 63, kb = (u >> 6) & 3, ot = u >> 8;
  const int o = ot * 16 + (lane & 15);
  const int c0 = kb * 32 + (lane >> 4) * 8;
  const float4* w = (const float4*)(W + (size_t)o * CIN + c0);
  float4 w0 = w[0], w1 = w[1];
  uint4 r;
  r.x = pack2(w0.x, w0.y); r.y = pack2(w0.z, w0.w);
  r.z = pack2(w1.x, w1.y); r.w = pack2(w1.z, w1.w);
  Wf[u] = r;
}

// ---------------------------------------------------------------------------
// Fused kernel, head-split: block = (b, g, 8x16 tile). 128 threads = 2 waves.
//  Phase A: x halo (10x18, OOB -> 0) -> MFMA B-frags in registers.
//  GEMM: 6 o-tiles (Q,K,V x 2) x 6 pos-tiles x 4 k-blocks of
//        mfma_f32_16x16x32_bf16; bf16 outputs to chunk-planar LDS
//        (Q interior-only). One barrier. Then per-thread attention.
// OOB halo positions have zero x-frags -> K=V=0 -> logit exactly 0 and zero
// V contribution == reference zero-pad semantics, branch-free.
// LDS = 8KB (Q) + 12KB (K) + 12KB (V) = 32KB exactly -> 5 blocks/CU.
// ---------------------------------------------------------------------------
__global__ __launch_bounds__(128) void fused_kernel(const float* __restrict__ x,
                                                    const uint4* __restrict__ Wf,
                                                    float* __restrict__ out) {
  __shared__ uint4 qs[4 * QP];     //  8 KB
  __shared__ uint4 ks[4 * NPOS];   // 12 KB
  __shared__ uint4 vs[4 * NPOS];   // 12 KB

  const int z  = blockIdx.z;
  const int b  = z >> 2, g = z & 3;              // head blocks of a tile: id stride 72 -> same XCD
  const int h0 = blockIdx.y * TH;
  const int w0 = blockIdx.x * TW;
  const int t  = threadIdx.x;
  const int wv = t >> 6, lane = t & 63;
  const int colp = lane & 15, quad = lane >> 4;

  // ---- Phase A: x halo -> B-fragments in registers ----
  // Wave wv owns pos-tiles wv*6 .. wv*6+5. Lane holds B[k=quad*8+j][col=colp].
  uint4 frags[6][4];
  {
    const size_t xbase = (size_t)b * CIN * HW;
#pragma unroll
    for (int i = 0; i < 6; ++i) {
      const int hp = (wv * 6 + i) * 16 + colp;
      const int hr = hp / HC, hc = hp - hr * HC;
      const int hh = h0 - 1 + hr, ww = w0 - 1 + hc;
      const bool ok = (hp < HP) & (hh >= 0) & (hh < HDIM) & (ww >= 0) & (ww < WDIM);
#pragma unroll
      for (int kb = 0; kb < 4; ++kb) {
        const int c0 = kb * 32 + quad * 8;
        float f[8] = {0.f, 0.f, 0.f, 0.f, 0.f, 0.f, 0.f, 0.f};
        if (ok) {
          const size_t pbyte = xbase + (size_t)(hh * WDIM + ww);
#pragma unroll
          for (int j = 0; j < 8; ++j) f[j] = x[pbyte + (size_t)(c0 + j) * HW];
        }
        uint4 r;
        r.x = pack2(f[0], f[1]); r.y = pack2(f[2], f[3]);
        r.z = pack2(f[4], f[5]); r.w = pack2(f[6], f[7]);
        frags[i][kb] = r;
      }
    }
  }

  // ---- GEMM for this head: s=0:Q, 1:K, 2:V; ph = lo/hi 16 of the 32 d ----
#pragma unroll
  for (int s = 0; s < 3; ++s) {
#pragma unroll
    for (int ph = 0; ph < 2; ++ph) {
      const int ot = s * 8 + g * 2 + ph;
      bf16x8 af[4];
#pragma unroll
      for (int kb = 0; kb < 4; ++kb) {
        uint4 tmp = Wf[(ot * 4 + kb) * 64 + lane];   // L2-hot, coalesced
        af[kb] = *(bf16x8*)&tmp;
      }
      const int d0 = ph * 16 + quad * 4;       // 4 consecutive d (regs 0..3)
      const int c = d0 >> 3, sub = (d0 >> 2) & 1;
#pragma unroll
      for (int i = 0; i < 6; ++i) {
        f32x4 acc = {0.f, 0.f, 0.f, 0.f};
#pragma unroll
        for (int kb = 0; kb < 4; ++kb)
          acc = __builtin_amdgcn_mfma_f32_16x16x32_bf16(
              af[kb], *(bf16x8*)&frags[i][kb], acc, 0, 0, 0);
        uint2 st;
        st.x = pack2(acc[0], acc[1]);
        st.y = pack2(acc[2], acc[3]);
        const int pos = (wv * 6 + i) * 16 + colp;
        if (s == 0) {
          // Q: interior positions only, compact [d-chunk][128]
          const int hr = pos / HC, hc = pos - hr * HC;
          if (((unsigned)(hr - 1) < TH) & ((unsigned)(hc - 1) < TW)) {
            const int idx = (hr - 1) * TW + (hc - 1);
            *(uint2*)((unsigned short*)(qs + c * QP + idx) + sub * 4) = st;
          }
        } else {
          uint4* dst = (s == 1) ? ks : vs;
          *(uint2*)((unsigned short*)(dst + c * NPOS + pos) + sub * 4) = st;
        }
      }
    }
  }
  __syncthreads();

  // ---- attention: thread t owns interior position t ----
  const int y = t >> 4, xx = t & 15;
  const int pbase = (y + 1) * HC + (xx + 1);

  float q[32];
#pragma unroll
  for (int c = 0; c < 4; ++c) {
    uint4 u = qs[c * QP + t];
    q[c * 8 + 0] = bflo(u.x); q[c * 8 + 1] = bfhi(u.x);
    q[c * 8 + 2] = bflo(u.y); q[c * 8 + 3] = bfhi(u.y);
    q[c * 8 + 4] = bflo(u.z); q[c * 8 + 5] = bfhi(u.z);
    q[c * 8 + 6] = bflo(u.w); q[c * 8 + 7] = bfhi(u.w);
  }

  float att[9];
#pragma unroll
  for (int nn = 0; nn < 9; ++nn) {
    const int pn = pbase + (nn / 3 - 1) * HC + (nn % 3 - 1);
    float dot = 0.0f;
#pragma unroll
    for (int c = 0; c < 4; ++c) {
      uint4 u = ks[c * NPOS + pn];
      dot = fmaf(q[c * 8 + 0], bflo(u.x), dot);
      dot = fmaf(q[c * 8 + 1], bfhi(u.x), dot);
      dot = fmaf(q[c * 8 + 2], bflo(u.y), dot);
      dot = fmaf(q[c * 8 + 3], bfhi(u.y), dot);
      dot = fmaf(q[c * 8 + 4], bflo(u.z), dot);
      dot = fmaf(q[c * 8 + 5], bfhi(u.z), dot);
      dot = fmaf(q[c * 8 + 6], bflo(u.w), dot);
      dot = fmaf(q[c * 8 + 7], bfhi(u.w), dot);
    }
    att[nn] = dot * 0.17677669529663687f;   // 1/sqrt(32)
  }

  float m = att[0];
#pragma unroll
  for (int nn = 1; nn < 9; ++nn) m = fmaxf(m, att[nn]);
  float s = 0.0f;
#pragma unroll
  for (int nn = 0; nn < 9; ++nn) { att[nn] = __expf(att[nn] - m); s += att[nn]; }
  const float inv = 1.0f / s;

  float acc[32];
#pragma unroll
  for (int i = 0; i < 32; ++i) acc[i] = 0.0f;
#pragma unroll
  for (int nn = 0; nn < 9; ++nn) {
    const float wn = att[nn] * inv;
    const int pn = pbase + (nn / 3 - 1) * HC + (nn % 3 - 1);
#pragma unroll
    for (int c = 0; c < 4; ++c) {
      uint4 u = vs[c * NPOS + pn];
      acc[c * 8 + 0] = fmaf(wn, bflo(u.x), acc[c * 8 + 0]);
      acc[c * 8 + 1] = fmaf(wn, bfhi(u.x), acc[c * 8 + 1]);
      acc[c * 8 + 2] = fmaf(wn, bflo(u.y), acc[c * 8 + 2]);
      acc[c * 8 + 3] = fmaf(wn, bfhi(u.y), acc[c * 8 + 3]);
      acc[c * 8 + 4] = fmaf(wn, bflo(u.z), acc[c * 8 + 4]);
      acc[c * 8 + 5] = fmaf(wn, bfhi(u.z), acc[c * 8 + 5]);
      acc[c * 8 + 6] = fmaf(wn, bflo(u.w), acc[c * 8 + 6]);
      acc[c * 8 + 7] = fmaf(wn, bfhi(u.w), acc[c * 8 + 7]);
    }
  }

  // out [b][C=128][96][96]; channel = g*32 + d; lanes along w -> coalesced
  float* ob = out + ((size_t)b * CIN + (size_t)g * DHEAD) * HW
            + (size_t)(h0 + y) * WDIM + (w0 + xx);
#pragma unroll
  for (int i = 0; i < 32; ++i) ob[(size_t)i * HW] = acc[i];
}

extern "C" void kernel_launch(void* const* d_in, const int* in_sizes, int n_in,
                              void* d_out, int out_size, void* d_ws, size_t ws_size,
                              hipStream_t stream) {
  (void)in_sizes; (void)n_in; (void)out_size; (void)ws_size;
  const float* x = (const float*)d_in[0];   // [8,128,96,96]
  const float* W = (const float*)d_in[1];   // [384,128]
  float* out = (float*)d_out;

  uint4* Wf = (uint4*)d_ws;                 // 96 KB packed weights

  wpack_kernel<<<24, 256, 0, stream>>>(W, Wf);
  fused_kernel<<<dim3(WDIM / TW, HDIM / TH, NB * HEADS), 128, 0, stream>>>(x, Wf, out);
}

// Round 5
// 129.898 us; speedup vs baseline: 1.2290x; 1.2290x over previous
//
#include <hip/hip_runtime.h>

// Problem constants: x [8,128,96,96] fp32, W [384,128] fp32, out [8,128,96,96] fp32.
#define NB     8
#define CIN    128
#define HEADS  4
#define DHEAD  32
#define HDIM   96
#define WDIM   96
#define HW     9216

// Fused-kernel tile geometry. One block = one (b, 8x16 spatial tile), 4 waves.
#define TH     8                 // interior rows per block
#define TW     16                // interior cols per block
#define HR     (TH + 2)          // halo rows = 10
#define HC     (TW + 2)          // halo cols = 18
#define HP     (HR * HC)         // halo positions = 180
#define NT     12                // position tiles of 16 (192 >= 180, pad OOB)
#define NPOS   (NT * 16)         // 192
#define NPOSP  (NPOS + 1)        // padded plane stride (uint4/float4 units)
#define QP     (TH * TW)         // 128 interior positions

// NOTE: gfx950 builtins (cvt_pkrtz / fdot2 / mfma_*_f16) use __fp16 vectors,
// NOT _Float16 vectors -- distinct types to clang (round-4 compile failure).
typedef __fp16 f16x2 __attribute__((ext_vector_type(2)));
typedef __fp16 f16x8 __attribute__((ext_vector_type(8)));
typedef float  f32x4 __attribute__((ext_vector_type(4)));

__device__ __forceinline__ unsigned pkh2(float a, float b) {
  f16x2 h = __builtin_amdgcn_cvt_pkrtz(a, b);    // v_cvt_pkrtz_f16_f32, 1 instr
  return *(unsigned*)&h;
}
__device__ __forceinline__ float dot2(unsigned a, unsigned b, float c) {
#if __has_builtin(__builtin_amdgcn_fdot2)
  return __builtin_amdgcn_fdot2(*(f16x2*)&a, *(f16x2*)&b, c, false);  // v_dot2_f32_f16
#else
  f16x2 ha = *(f16x2*)&a, hb = *(f16x2*)&b;
  c = fmaf((float)ha[0], (float)hb[0], c);
  return fmaf((float)ha[1], (float)hb[1], c);
#endif
}

// ---------------------------------------------------------------------------
// Prep: pack W [384][128] fp32 into A-fragment-ordered f16 global buffer.
// Frag (ot,kb): lane l holds A[o=ot*16+(l&15)][c=kb*32+(l>>4)*8+j], j=0..7 (16B).
// ---------------------------------------------------------------------------
__global__ __launch_bounds__(256) void wpack_kernel(const float* __restrict__ W,
                                                    uint4* __restrict__ Wf) {
  const int u = blockIdx.x * 256 + threadIdx.x;   // 0..6143 = 24 ot * 4 kb * 64 lanes
  const int lane = u & 63, kb = (u >> 6) & 3, ot = u >> 8;
  const int o = ot * 16 + (lane & 15);
  const int c0 = kb * 32 + (lane >> 4) * 8;
  const float4* w = (const float4*)(W + (size_t)o * CIN + c0);
  float4 w0 = w[0], w1 = w[1];
  uint4 r;
  r.x = pkh2(w0.x, w0.y); r.y = pkh2(w0.z, w0.w);
  r.z = pkh2(w1.x, w1.y); r.w = pkh2(w1.z, w1.w);
  Wf[u] = r;
}

// ---------------------------------------------------------------------------
// Fused kernel: block = (b, 8x16 tile), 256 threads = 4 waves.
//  Phase A: x halo (10x18, OOB -> 0) -> f16 MFMA B-frags; wave wv owns
//           pos-tiles wv*3 .. wv*3+2 (frags[3][4] = 48 VGPR).
//  Per head g: GEMM 6 o-tiles x 3 pos-tiles x 4 kb mfma_f32_16x16x32_f16;
//           Q,K packed f16 to LDS; V fp32 to LDS. Barrier. Attention:
//           thread = (pos, d-half); logits via v_dot2_f32_f16 (full d),
//           PV via v_fmac_f32 on fp32 V (16 d per thread).
// OOB halo positions have zero x-frags -> K=V=0 -> logit exactly 0, zero V
// contribution == reference zero-pad semantics, branch-free.
// LDS: Q 8KB (f16, interior) + K 12.35KB (f16, padded) + V 24.7KB (fp32,
// padded) = 45.2KB -> 3 blocks/CU, 12 waves/CU.
// ---------------------------------------------------------------------------
__global__ __launch_bounds__(256) void fused_kernel(const float* __restrict__ x,
                                                    const uint4* __restrict__ Wf,
                                                    float* __restrict__ out) {
  __shared__ uint4 qs[4 * QP];      //  8 KB   f16, interior positions only
  __shared__ uint4 ks[4 * NPOSP];   // 12.35 KB f16, halo
  __shared__ f32x4 vs[8 * NPOSP];   // 24.7 KB fp32, halo

  const int b  = blockIdx.z;
  const int h0 = blockIdx.y * TH;
  const int w0 = blockIdx.x * TW;
  const int t  = threadIdx.x;
  const int wv = t >> 6, lane = t & 63;
  const int colp = lane & 15, quad = lane >> 4;

  // ---- Phase A: x halo -> f16 B-fragments in registers ----
  uint4 frags[3][4];
  {
    const size_t xbase = (size_t)b * CIN * HW;
#pragma unroll
    for (int i = 0; i < 3; ++i) {
      const int hp = (wv * 3 + i) * 16 + colp;
      const int hr = hp / HC, hc = hp - hr * HC;
      const int hh = h0 - 1 + hr, ww = w0 - 1 + hc;
      const bool ok = (hp < HP) & (hh >= 0) & (hh < HDIM) & (ww >= 0) & (ww < WDIM);
#pragma unroll
      for (int kb = 0; kb < 4; ++kb) {
        const int c0 = kb * 32 + quad * 8;
        float f[8] = {0.f, 0.f, 0.f, 0.f, 0.f, 0.f, 0.f, 0.f};
        if (ok) {
          const size_t pb = xbase + (size_t)(hh * WDIM + ww);
#pragma unroll
          for (int j = 0; j < 8; ++j) f[j] = x[pb + (size_t)(c0 + j) * HW];
        }
        uint4 r;
        r.x = pkh2(f[0], f[1]); r.y = pkh2(f[2], f[3]);
        r.z = pkh2(f[4], f[5]); r.w = pkh2(f[6], f[7]);
        frags[i][kb] = r;
      }
    }
  }

  // attn identity: thread = (pos, d-half)
  const int pos = t & 127, dh = t >> 7;
  const int y = pos >> 4, xx = pos & 15;
  const int pbase = (y + 1) * HC + (xx + 1);

#pragma unroll 1
  for (int g = 0; g < 4; ++g) {
    if (g) __syncthreads();                      // prev head's attn reads done

    // ---- GEMM for head g: s=0:Q, 1:K, 2:V; ph = lo/hi 16 of 32 d ----
#pragma unroll
    for (int s = 0; s < 3; ++s) {
#pragma unroll
      for (int ph = 0; ph < 2; ++ph) {
        const int ot = s * 8 + g * 2 + ph;
        f16x8 af[4];
#pragma unroll
        for (int kb = 0; kb < 4; ++kb) {
          uint4 tmp = Wf[(ot * 4 + kb) * 64 + lane];   // L2-hot, coalesced
          af[kb] = *(f16x8*)&tmp;
        }
        const int d0 = ph * 16 + quad * 4;       // 4 consecutive d (regs 0..3)
#pragma unroll
        for (int i = 0; i < 3; ++i) {
          f32x4 acc = {0.f, 0.f, 0.f, 0.f};
#pragma unroll
          for (int kb = 0; kb < 4; ++kb)
            acc = __builtin_amdgcn_mfma_f32_16x16x32_f16(
                af[kb], *(f16x8*)&frags[i][kb], acc, 0, 0, 0);
          const int pw = (wv * 3 + i) * 16 + colp;
          if (s == 2) {
            vs[(d0 >> 2) * NPOSP + pw] = acc;    // fp32 V, ds_write_b128
          } else {
            uint2 st;
            st.x = pkh2(acc[0], acc[1]);
            st.y = pkh2(acc[2], acc[3]);
            if (s == 0) {
              const int hr = pw / HC, hc = pw - hr * HC;
              if (((unsigned)(hr - 1) < TH) & ((unsigned)(hc - 1) < TW)) {
                const int idx = (hr - 1) * TW + (hc - 1);
                *(uint2*)((unsigned short*)(qs + (d0 >> 3) * QP + idx)
                          + ((d0 >> 2) & 1) * 4) = st;
              }
            } else {
              *(uint2*)((unsigned short*)(ks + (d0 >> 3) * NPOSP + pw)
                        + ((d0 >> 2) & 1) * 4) = st;
            }
          }
        }
      }
    }
    __syncthreads();

    // ---- attention for head g ----
    unsigned qp[16];                              // 16 x half2 = full 32-d Q
#pragma unroll
    for (int c = 0; c < 4; ++c) {
      uint4 u = qs[c * QP + pos];
      qp[c * 4 + 0] = u.x; qp[c * 4 + 1] = u.y;
      qp[c * 4 + 2] = u.z; qp[c * 4 + 3] = u.w;
    }

    float att[9];
#pragma unroll
    for (int nn = 0; nn < 9; ++nn) {
      const int pn = pbase + (nn / 3 - 1) * HC + (nn % 3 - 1);
      float dot = 0.0f;
#pragma unroll
      for (int c = 0; c < 4; ++c) {
        uint4 ku = ks[c * NPOSP + pn];
        dot = dot2(qp[c * 4 + 0], ku.x, dot);
        dot = dot2(qp[c * 4 + 1], ku.y, dot);
        dot = dot2(qp[c * 4 + 2], ku.z, dot);
        dot = dot2(qp[c * 4 + 3], ku.w, dot);
      }
      att[nn] = dot * 0.17677669529663687f;   // 1/sqrt(32)
    }

    float m = att[0];
#pragma unroll
    for (int nn = 1; nn < 9; ++nn) m = fmaxf(m, att[nn]);
    float ssum = 0.0f;
#pragma unroll
    for (int nn = 0; nn < 9; ++nn) { att[nn] = __expf(att[nn] - m); ssum += att[nn]; }
    const float inv = 1.0f / ssum;

    f32x4 acc4[4];
#pragma unroll
    for (int j = 0; j < 4; ++j) acc4[j] = (f32x4){0.f, 0.f, 0.f, 0.f};
#pragma unroll
    for (int nn = 0; nn < 9; ++nn) {
      const float wn = att[nn] * inv;
      const int pn = pbase + (nn / 3 - 1) * HC + (nn % 3 - 1);
#pragma unroll
      for (int j = 0; j < 4; ++j) {
        f32x4 vv = vs[(dh * 4 + j) * NPOSP + pn];
        acc4[j] += wn * vv;                      // 4x v_fmac_f32
      }
    }

    // out [b][C=128][96][96]; channel = g*32 + dh*16 + j*4 + e
    float* ob = out + ((size_t)b * CIN + (size_t)g * DHEAD + (size_t)dh * 16) * HW
              + (size_t)(h0 + y) * WDIM + (w0 + xx);
#pragma unroll
    for (int j = 0; j < 4; ++j)
#pragma unroll
      for (int e = 0; e < 4; ++e)
        ob[(size_t)(j * 4 + e) * HW] = acc4[j][e];
  }
}

extern "C" void kernel_launch(void* const* d_in, const int* in_sizes, int n_in,
                              void* d_out, int out_size, void* d_ws, size_t ws_size,
                              hipStream_t stream) {
  (void)in_sizes; (void)n_in; (void)out_size; (void)ws_size;
  const float* x = (const float*)d_in[0];   // [8,128,96,96]
  const float* W = (const float*)d_in[1];   // [384,128]
  float* out = (float*)d_out;

  uint4* Wf = (uint4*)d_ws;                 // 96 KB packed weights

  wpack_kernel<<<24, 256, 0, stream>>>(W, Wf);
  fused_kernel<<<dim3(WDIM / TW, HDIM / TH, NB), 256, 0, stream>>>(x, Wf, out);
}